// Round 1
// 557.448 us; speedup vs baseline: 1.0310x; 1.0310x over previous
//
#include <hip/hip_runtime.h>

// VolAttn3d: B=1, N=4, C=16, D=64, H=128, W=128
// scores[n] = (1/4) * sum_c q[c]*k[n,c]   (per voxel)
// attn = softmax_n(scores)
// x[c] = sum_n attn[n]*v[n,c]
// out[o] = b[o] + sum_c w[o,c]*x[c]
//
// R5: float4/thread (16 B/lane streaming — the m13 6.3 TB/s ceiling was
// measured at this width). Register-pressure-aware restructuring:
//  - score phase: c outer / n inner, q[c] transient  -> 16 live acc regs
//  - output phase: projection fused into v loop, x[] never materialized
//    (acc[o] += w[o,c]*xt)                           -> 64+16 live regs
//  - nontemporal loads on q/k/v (read-once streams) + nt stores.

constexpr int C = 16;
constexpr int N = 4;
constexpr int DHW = 64 * 128 * 128;  // 1048576 voxels

typedef float v4f __attribute__((ext_vector_type(4)));

__global__ __launch_bounds__(256) void volattn3d_kernel(
    const float* __restrict__ q,
    const float* __restrict__ k,
    const float* __restrict__ v,
    const float* __restrict__ w,   // (C_out=16, C_in=16) row-major
    const float* __restrict__ b,   // (16,)
    float* __restrict__ out)
{
    const int t = blockIdx.x * blockDim.x + threadIdx.x;  // float4 index
    if (t >= DHW / 4) return;
    const size_t s = (size_t)t * 4;  // element offset

    // ---- scores: sc[n][j] = sum_c q[c][j]*k[n,c][j]  (scale later) ----
    float sc[N][4];
#pragma unroll
    for (int n = 0; n < N; ++n)
#pragma unroll
        for (int j = 0; j < 4; ++j) sc[n][j] = 0.f;

#pragma unroll
    for (int c = 0; c < C; ++c) {
        const v4f qv = __builtin_nontemporal_load(
            reinterpret_cast<const v4f*>(q + (size_t)c * DHW + s));
#pragma unroll
        for (int n = 0; n < N; ++n) {
            const v4f kv = __builtin_nontemporal_load(
                reinterpret_cast<const v4f*>(k + (size_t)(n * C + c) * DHW + s));
#pragma unroll
            for (int j = 0; j < 4; ++j)
                sc[n][j] = fmaf(qv[j], kv[j], sc[n][j]);
        }
    }

    // ---- softmax over n (4 elements), per component ----
    float p[N][4];
#pragma unroll
    for (int j = 0; j < 4; ++j) {
        const float s0 = sc[0][j] * 0.25f;
        const float s1 = sc[1][j] * 0.25f;
        const float s2 = sc[2][j] * 0.25f;
        const float s3 = sc[3][j] * 0.25f;
        const float m = fmaxf(fmaxf(s0, s1), fmaxf(s2, s3));
        const float e0 = __expf(s0 - m);
        const float e1 = __expf(s1 - m);
        const float e2 = __expf(s2 - m);
        const float e3 = __expf(s3 - m);
        const float inv = 1.f / (e0 + e1 + e2 + e3);
        p[0][j] = e0 * inv;
        p[1][j] = e1 * inv;
        p[2][j] = e2 * inv;
        p[3][j] = e3 * inv;
    }

    // ---- fused x + projection: acc[o] = b[o] + sum_c w[o,c] * xt_c ----
    float acc[C][4];
#pragma unroll
    for (int o = 0; o < C; ++o) {
        const float bo = b[o];
#pragma unroll
        for (int j = 0; j < 4; ++j) acc[o][j] = bo;
    }

#pragma unroll
    for (int c = 0; c < C; ++c) {
        float xt[4] = {0.f, 0.f, 0.f, 0.f};
#pragma unroll
        for (int n = 0; n < N; ++n) {
            const v4f vv = __builtin_nontemporal_load(
                reinterpret_cast<const v4f*>(v + (size_t)(n * C + c) * DHW + s));
#pragma unroll
            for (int j = 0; j < 4; ++j)
                xt[j] = fmaf(p[n][j], vv[j], xt[j]);
        }
#pragma unroll
        for (int o = 0; o < C; ++o) {
            const float wc = w[o * C + c];
#pragma unroll
            for (int j = 0; j < 4; ++j)
                acc[o][j] = fmaf(wc, xt[j], acc[o][j]);
        }
    }

    // ---- nontemporal store (16 B/lane) ----
#pragma unroll
    for (int o = 0; o < C; ++o) {
        v4f r;
        r.x = acc[o][0];
        r.y = acc[o][1];
        r.z = acc[o][2];
        r.w = acc[o][3];
        __builtin_nontemporal_store(
            r, reinterpret_cast<v4f*>(out + (size_t)o * DHW + s));
    }
}

extern "C" void kernel_launch(void* const* d_in, const int* in_sizes, int n_in,
                              void* d_out, int out_size, void* d_ws, size_t ws_size,
                              hipStream_t stream) {
    const float* q = (const float*)d_in[0];
    const float* k = (const float*)d_in[1];
    const float* v = (const float*)d_in[2];
    const float* w = (const float*)d_in[3];
    const float* b = (const float*)d_in[4];
    float* out = (float*)d_out;

    const int threads = 256;
    const int total = DHW / 4;            // 262144 threads
    const int blocks = (total + threads - 1) / threads;  // 1024 blocks
    volattn3d_kernel<<<blocks, threads, 0, stream>>>(q, k, v, w, b, out);
}

// Round 2
// 544.336 us; speedup vs baseline: 1.0558x; 1.0241x over previous
//
#include <hip/hip_runtime.h>

// VolAttn3d: B=1, N=4, C=16, D=64, H=128, W=128
// scores[n] = (1/4) * sum_c q[c]*k[n,c]   (per voxel)
// attn = softmax_n(scores)
// x[c] = sum_n attn[n]*v[n,c]
// out[o] = b[o] + sum_c w[o,c]*x[c]
//
// R6: DRAM row-locality round.
//  - 1024-thread blocks (256 blocks = 1/CU): each stream visited for
//    16 KiB contiguous per block (vs 4 KiB at 256 threads) -> 4x fewer
//    row activations per byte across the 36 concurrent 4 MiB-strided
//    streams. Occupancy unchanged: 16 waves/CU either way.
//  - __launch_bounds__(1024) caps VGPR at 128 (needed for 4 waves/SIMD);
//    softmax done in-place in sc[] to keep pressure under the cap.
//  - per-block rotation of the c stream order (commutative in both
//    phases) decorrelates which DRAM rows same-phase blocks hit.
//  - float4 (16 B/lane) nontemporal streaming loads + nt stores (R5).

constexpr int C = 16;
constexpr int N = 4;
constexpr int DHW = 64 * 128 * 128;  // 1048576 voxels

typedef float v4f __attribute__((ext_vector_type(4)));

__global__ __launch_bounds__(1024) void volattn3d_kernel(
    const float* __restrict__ q,
    const float* __restrict__ k,
    const float* __restrict__ v,
    const float* __restrict__ w,   // (C_out=16, C_in=16) row-major
    const float* __restrict__ b,   // (16,)
    float* __restrict__ out)
{
    const int t = blockIdx.x * blockDim.x + threadIdx.x;  // float4 index
    if (t >= DHW / 4) return;
    const size_t s = (size_t)t * 4;       // element offset
    const int c0 = blockIdx.x & 15;       // per-block stream rotation

    // ---- scores: sc[n][j] = sum_c q[c][j]*k[n,c][j]  (scale later) ----
    float sc[N][4];
#pragma unroll
    for (int n = 0; n < N; ++n)
#pragma unroll
        for (int j = 0; j < 4; ++j) sc[n][j] = 0.f;

#pragma unroll
    for (int ci = 0; ci < C; ++ci) {
        const int c = (ci + c0) & 15;     // block-uniform rotated stream
        const v4f qv = __builtin_nontemporal_load(
            reinterpret_cast<const v4f*>(q + (size_t)c * DHW + s));
#pragma unroll
        for (int n = 0; n < N; ++n) {
            const v4f kv = __builtin_nontemporal_load(
                reinterpret_cast<const v4f*>(k + (size_t)(n * C + c) * DHW + s));
#pragma unroll
            for (int j = 0; j < 4; ++j)
                sc[n][j] = fmaf(qv[j], kv[j], sc[n][j]);
        }
    }

    // ---- softmax over n (4 elements), in place to save registers ----
#pragma unroll
    for (int j = 0; j < 4; ++j) {
        const float s0 = sc[0][j] * 0.25f;
        const float s1 = sc[1][j] * 0.25f;
        const float s2 = sc[2][j] * 0.25f;
        const float s3 = sc[3][j] * 0.25f;
        const float m = fmaxf(fmaxf(s0, s1), fmaxf(s2, s3));
        const float e0 = __expf(s0 - m);
        const float e1 = __expf(s1 - m);
        const float e2 = __expf(s2 - m);
        const float e3 = __expf(s3 - m);
        const float inv = 1.f / (e0 + e1 + e2 + e3);
        sc[0][j] = e0 * inv;
        sc[1][j] = e1 * inv;
        sc[2][j] = e2 * inv;
        sc[3][j] = e3 * inv;
    }

    // ---- fused x + projection: acc[o] = b[o] + sum_c w[o,c] * xt_c ----
    float acc[C][4];
#pragma unroll
    for (int o = 0; o < C; ++o) {
        const float bo = b[o];
#pragma unroll
        for (int j = 0; j < 4; ++j) acc[o][j] = bo;
    }

#pragma unroll
    for (int ci = 0; ci < C; ++ci) {
        const int c = (ci + c0) & 15;     // rotated v-stream order
        float xt[4] = {0.f, 0.f, 0.f, 0.f};
#pragma unroll
        for (int n = 0; n < N; ++n) {
            const v4f vv = __builtin_nontemporal_load(
                reinterpret_cast<const v4f*>(v + (size_t)(n * C + c) * DHW + s));
#pragma unroll
            for (int j = 0; j < 4; ++j)
                xt[j] = fmaf(sc[n][j], vv[j], xt[j]);
        }
#pragma unroll
        for (int o = 0; o < C; ++o) {
            const float wc = w[o * C + c];
#pragma unroll
            for (int j = 0; j < 4; ++j)
                acc[o][j] = fmaf(wc, xt[j], acc[o][j]);
        }
    }

    // ---- nontemporal store (16 B/lane) ----
#pragma unroll
    for (int o = 0; o < C; ++o) {
        v4f r;
        r.x = acc[o][0];
        r.y = acc[o][1];
        r.z = acc[o][2];
        r.w = acc[o][3];
        __builtin_nontemporal_store(
            r, reinterpret_cast<v4f*>(out + (size_t)o * DHW + s));
    }
}

extern "C" void kernel_launch(void* const* d_in, const int* in_sizes, int n_in,
                              void* d_out, int out_size, void* d_ws, size_t ws_size,
                              hipStream_t stream) {
    const float* q = (const float*)d_in[0];
    const float* k = (const float*)d_in[1];
    const float* v = (const float*)d_in[2];
    const float* w = (const float*)d_in[3];
    const float* b = (const float*)d_in[4];
    float* out = (float*)d_out;

    const int threads = 1024;
    const int total = DHW / 4;                            // 262144 threads
    const int blocks = (total + threads - 1) / threads;   // 256 blocks
    volattn3d_kernel<<<blocks, threads, 0, stream>>>(q, k, v, w, b, out);
}